// Round 1
// baseline (6457.230 us; speedup 1.0000x reference)
//
#include <hip/hip_runtime.h>
#include <math.h>

#define N_NODES 100000
#define N_EDGES 3200000
#define H 10
#define S 12          // padded per-node stride (floats): 48B -> float4-aligned for all i
#define IN_DIM 16

// ---------------- node: x_ = x@iW + ib ; deg = 1 (self loop) ----------------
__global__ __launch_bounds__(256) void k_init(const float* __restrict__ x,
    const float* __restrict__ iW, const float* __restrict__ ib,
    float* __restrict__ x_, float* __restrict__ deg)
{
    int i = blockIdx.x * 256 + threadIdx.x;
    if (i >= N_NODES) return;
    const float4* xv = (const float4*)(x + (size_t)i * IN_DIM);
    float xi[IN_DIM];
    float4 a0 = xv[0], a1 = xv[1], a2 = xv[2], a3 = xv[3];
    xi[0]=a0.x; xi[1]=a0.y; xi[2]=a0.z; xi[3]=a0.w;
    xi[4]=a1.x; xi[5]=a1.y; xi[6]=a1.z; xi[7]=a1.w;
    xi[8]=a2.x; xi[9]=a2.y; xi[10]=a2.z; xi[11]=a2.w;
    xi[12]=a3.x; xi[13]=a3.y; xi[14]=a3.z; xi[15]=a3.w;
    #pragma unroll
    for (int j = 0; j < H; ++j) {
        float acc = ib[j];
        #pragma unroll
        for (int k = 0; k < IN_DIM; ++k) acc = fmaf(xi[k], iW[k*H + j], acc);
        x_[(size_t)i*S + j] = acc;
        deg[(size_t)i*S + j] = 1.0f;
    }
}

// ---------------- edge: deg[col] += ew ----------------
__global__ __launch_bounds__(256) void k_deg(const int* __restrict__ ei,
    const float* __restrict__ attr, const float* __restrict__ W1,
    const float* __restrict__ W2, float* __restrict__ deg)
{
    __shared__ float sW1[4*H], sW2[H*H];
    int t = threadIdx.x;
    if (t < 4*H) sW1[t] = W1[t];
    int u = t - 128;
    if (u >= 0 && u < H*H) sW2[u] = W2[u];
    __syncthreads();
    int e = blockIdx.x * 256 + t;
    if (e >= N_EDGES) return;
    int c = ei[N_EDGES + e];
    float4 a = *(const float4*)(attr + (size_t)e * 4);
    float tt[H];
    #pragma unroll
    for (int j = 0; j < H; ++j)
        tt[j] = fmaxf(fmaf(a.x, sW1[j], fmaf(a.y, sW1[H+j],
                      fmaf(a.z, sW1[2*H+j], a.w*sW1[3*H+j]))), 0.f);
    float* dst = deg + (size_t)c * S;
    #pragma unroll
    for (int ch = 0; ch < H; ++ch) {
        float v = 0.f;
        #pragma unroll
        for (int j = 0; j < H; ++j) v = fmaf(tt[j], sW2[j*H + ch], v);
        unsafeAtomicAdd(dst + ch, fmaxf(v, 0.f));
    }
}

// ---------------- node: dinv = rsqrt(deg) (in place); layer-0 xp/agg init ----------------
__global__ __launch_bounds__(256) void k_prep(float* __restrict__ deg_dinv,
    const float* __restrict__ x_, const float* __restrict__ gw,
    const float* __restrict__ gb, float* __restrict__ xp, float* __restrict__ agg)
{
    int i = blockIdx.x * 256 + threadIdx.x;
    if (i >= N_NODES) return;
    #pragma unroll
    for (int ch = 0; ch < H; ++ch) {
        float d  = deg_dinv[(size_t)i*S + ch];
        float di = 1.0f / sqrtf(d);          // deg >= 1 always (self loop)
        deg_dinv[(size_t)i*S + ch] = di;
        float p = fmaxf(x_[(size_t)i*S + ch], 0.f) * gw[ch];
        xp[(size_t)i*S + ch]  = p;
        agg[(size_t)i*S + ch] = di*di*p + gb[ch];   // self-loop term + bias
    }
}

// ---------------- edge: agg[col] += dinv[row]*ew*dinv[col]*xp[row] ----------------
__global__ __launch_bounds__(256) void k_edge(const int* __restrict__ ei,
    const float* __restrict__ attr, const float* __restrict__ W1,
    const float* __restrict__ W2, const float* __restrict__ dinv,
    const float* __restrict__ xp, float* __restrict__ agg)
{
    __shared__ float sW1[4*H], sW2[H*H];
    int t = threadIdx.x;
    if (t < 4*H) sW1[t] = W1[t];
    int u = t - 128;
    if (u >= 0 && u < H*H) sW2[u] = W2[u];
    __syncthreads();
    int e = blockIdx.x * 256 + t;
    if (e >= N_EDGES) return;
    int r = ei[e];
    int c = ei[N_EDGES + e];
    float4 a = *(const float4*)(attr + (size_t)e * 4);
    float tt[H];
    #pragma unroll
    for (int j = 0; j < H; ++j)
        tt[j] = fmaxf(fmaf(a.x, sW1[j], fmaf(a.y, sW1[H+j],
                      fmaf(a.z, sW1[2*H+j], a.w*sW1[3*H+j]))), 0.f);
    const float4* dr4 = (const float4*)(dinv + (size_t)r * S);
    const float4* dc4 = (const float4*)(dinv + (size_t)c * S);
    const float4* xr4 = (const float4*)(xp   + (size_t)r * S);
    float dr[12], dc[12], xr[12];
    float4 b;
    b = dr4[0]; dr[0]=b.x; dr[1]=b.y; dr[2]=b.z; dr[3]=b.w;
    b = dr4[1]; dr[4]=b.x; dr[5]=b.y; dr[6]=b.z; dr[7]=b.w;
    b = dr4[2]; dr[8]=b.x; dr[9]=b.y;
    b = dc4[0]; dc[0]=b.x; dc[1]=b.y; dc[2]=b.z; dc[3]=b.w;
    b = dc4[1]; dc[4]=b.x; dc[5]=b.y; dc[6]=b.z; dc[7]=b.w;
    b = dc4[2]; dc[8]=b.x; dc[9]=b.y;
    b = xr4[0]; xr[0]=b.x; xr[1]=b.y; xr[2]=b.z; xr[3]=b.w;
    b = xr4[1]; xr[4]=b.x; xr[5]=b.y; xr[6]=b.z; xr[7]=b.w;
    b = xr4[2]; xr[8]=b.x; xr[9]=b.y;
    float* dst = agg + (size_t)c * S;
    #pragma unroll
    for (int ch = 0; ch < H; ++ch) {
        float v = 0.f;
        #pragma unroll
        for (int j = 0; j < H; ++j) v = fmaf(tt[j], sW2[j*H + ch], v);
        v = fmaxf(v, 0.f);
        unsafeAtomicAdd(dst + ch, dr[ch]*v*dc[ch]*xr[ch]);
    }
}

// ---------------- node: h = [x_,agg]@lin + x_ ; next xp/agg init OR final output ----------------
__global__ __launch_bounds__(256) void k_update(const float* __restrict__ x_,
    float* __restrict__ agg, const float* __restrict__ dinv,
    const float* __restrict__ lin, const float* __restrict__ gw,
    const float* __restrict__ gb, const float* __restrict__ oW,
    float* __restrict__ xp, float* __restrict__ out, int last)
{
    int i = blockIdx.x * 256 + threadIdx.x;
    if (i >= N_NODES) return;
    const float4* xq = (const float4*)(x_  + (size_t)i*S);
    const float4* aq = (const float4*)(agg + (size_t)i*S);
    float xv[12], av[12];
    float4 b;
    b = xq[0]; xv[0]=b.x; xv[1]=b.y; xv[2]=b.z; xv[3]=b.w;
    b = xq[1]; xv[4]=b.x; xv[5]=b.y; xv[6]=b.z; xv[7]=b.w;
    b = xq[2]; xv[8]=b.x; xv[9]=b.y;
    b = aq[0]; av[0]=b.x; av[1]=b.y; av[2]=b.z; av[3]=b.w;
    b = aq[1]; av[4]=b.x; av[5]=b.y; av[6]=b.z; av[7]=b.w;
    b = aq[2]; av[8]=b.x; av[9]=b.y;
    float h[H];
    #pragma unroll
    for (int j = 0; j < H; ++j) {
        float acc = xv[j];                       // residual
        #pragma unroll
        for (int k = 0; k < H; ++k) acc = fmaf(xv[k], lin[k*H + j], acc);
        #pragma unroll
        for (int k = 0; k < H; ++k) acc = fmaf(av[k], lin[(H+k)*H + j], acc);
        h[j] = acc;
    }
    if (!last) {
        #pragma unroll
        for (int ch = 0; ch < H; ++ch) {
            float p = fmaxf(h[ch], 0.f) * gw[ch];
            xp[(size_t)i*S + ch] = p;
            float di = dinv[(size_t)i*S + ch];
            agg[(size_t)i*S + ch] = di*di*p + gb[ch];
        }
    } else {
        float z0 = 0.f, z1 = 0.f;
        #pragma unroll
        for (int k = 0; k < H; ++k) { z0 = fmaf(xv[k], oW[2*k],   z0);
                                      z1 = fmaf(xv[k], oW[2*k+1], z1); }
        #pragma unroll
        for (int k = 0; k < H; ++k) { float hr = fmaxf(h[k], 0.f);
                                      z0 = fmaf(hr, oW[2*(H+k)],   z0);
                                      z1 = fmaf(hr, oW[2*(H+k)+1], z1); }
        out[i] = 1.0f / (1.0f + expf(z0 - z1));   // softmax -> column 1
    }
}

extern "C" void kernel_launch(void* const* d_in, const int* in_sizes, int n_in,
                              void* d_out, int out_size, void* d_ws, size_t ws_size,
                              hipStream_t stream)
{
    const float* x     = (const float*)d_in[0];
    const int*   ei    = (const int*)  d_in[1];
    const float* attr  = (const float*)d_in[2];
    const float* ew_W1 = (const float*)d_in[3];
    const float* ew_W2 = (const float*)d_in[4];
    const float* iW    = (const float*)d_in[5];
    const float* ib    = (const float*)d_in[6];
    const float* gcn_w = (const float*)d_in[7];
    const float* gcn_b = (const float*)d_in[8];
    const float* lin_W = (const float*)d_in[9];
    const float* oW    = (const float*)d_in[10];
    float* out = (float*)d_out;
    float* ws  = (float*)d_ws;

    float* x_   = ws;
    float* dinv = ws + (size_t)N_NODES * S;       // holds deg first, then dinv
    float* xp   = ws + (size_t)2 * N_NODES * S;
    float* agg  = ws + (size_t)3 * N_NODES * S;

    dim3 blk(256);
    dim3 ngrid((N_NODES + 255) / 256);
    dim3 egrid((N_EDGES + 255) / 256);

    k_init<<<ngrid, blk, 0, stream>>>(x, iW, ib, x_, dinv);
    k_deg <<<egrid, blk, 0, stream>>>(ei, attr, ew_W1, ew_W2, dinv);
    k_prep<<<ngrid, blk, 0, stream>>>(dinv, x_, gcn_w, gcn_b, xp, agg);

    // layer 0
    k_edge  <<<egrid, blk, 0, stream>>>(ei, attr, ew_W1, ew_W2, dinv, xp, agg);
    k_update<<<ngrid, blk, 0, stream>>>(x_, agg, dinv, lin_W + 0*2*H*H,
                                        gcn_w + 1*H, gcn_b + 1*H, oW, xp, out, 0);
    // layer 1
    k_edge  <<<egrid, blk, 0, stream>>>(ei, attr, ew_W1, ew_W2, dinv, xp, agg);
    k_update<<<ngrid, blk, 0, stream>>>(x_, agg, dinv, lin_W + 1*2*H*H,
                                        gcn_w + 2*H, gcn_b + 2*H, oW, xp, out, 0);
    // layer 2 (final)
    k_edge  <<<egrid, blk, 0, stream>>>(ei, attr, ew_W1, ew_W2, dinv, xp, agg);
    k_update<<<ngrid, blk, 0, stream>>>(x_, agg, dinv, lin_W + 2*2*H*H,
                                        nullptr, nullptr, oW, xp, out, 1);
}

// Round 3
// 601.383 us; speedup vs baseline: 10.7373x; 10.7373x over previous
//
#include <hip/hip_runtime.h>
#include <math.h>

#define N_NODES 100000
#define N_EDGES 3200000
#define H 10
#define S 12          // padded per-node stride (floats): 48B, float4-aligned
#define IN_DIM 16
#define NBLK_SCAN 98  // ceil(100000/1024)

// ============ build phase: counting sort of edges by col ============

__global__ __launch_bounds__(256) void k_count(const int* __restrict__ ei,
                                               int* __restrict__ cnt)
{
    int e = blockIdx.x * 256 + threadIdx.x;
    if (e >= N_EDGES) return;
    atomicAdd(&cnt[ei[N_EDGES + e]], 1);
}

__global__ __launch_bounds__(1024) void k_scan1(const int* __restrict__ cnt,
    int* __restrict__ chunkscan, int* __restrict__ bsum)
{
    __shared__ int buf[2][1024];
    int tid = threadIdx.x;
    int gid = blockIdx.x * 1024 + tid;
    int v = (gid < N_NODES) ? cnt[gid] : 0;
    int cur = 0;
    buf[0][tid] = v;
    __syncthreads();
    int x = v;
    for (int off = 1; off < 1024; off <<= 1) {
        int t = (tid >= off) ? buf[cur][tid - off] : 0;
        x = buf[cur][tid] + t;
        buf[cur ^ 1][tid] = x;
        cur ^= 1;
        __syncthreads();
    }
    x = buf[cur][tid];
    if (gid < N_NODES) chunkscan[gid] = x - v;      // exclusive within chunk
    if (tid == 1023) bsum[blockIdx.x] = x;          // chunk total
}

__global__ __launch_bounds__(128) void k_scan2(int* __restrict__ bsum)
{
    __shared__ int buf[2][128];
    int tid = threadIdx.x;
    int v = (tid < NBLK_SCAN) ? bsum[tid] : 0;
    int cur = 0;
    buf[0][tid] = v;
    __syncthreads();
    int x = v;
    for (int off = 1; off < 128; off <<= 1) {
        int t = (tid >= off) ? buf[cur][tid - off] : 0;
        x = buf[cur][tid] + t;
        buf[cur ^ 1][tid] = x;
        cur ^= 1;
        __syncthreads();
    }
    x = buf[cur][tid];
    if (tid < NBLK_SCAN) bsum[tid] = x - v;         // exclusive over chunks
}

__global__ __launch_bounds__(256) void k_scan3(int* __restrict__ start,
    const int* __restrict__ bsum, int* __restrict__ ptr)
{
    int i = blockIdx.x * 256 + threadIdx.x;
    if (i >= N_NODES) return;
    int s = start[i] + bsum[i >> 10];
    start[i] = s;
    ptr[i] = s;
}

// entry = 32B: {attr.x,.y,.z,.w, row_bits, pad, pad, pad}
__global__ __launch_bounds__(256) void k_fill(const int* __restrict__ ei,
    const float* __restrict__ attr, int* __restrict__ ptr,
    float4* __restrict__ entries)
{
    int e = blockIdx.x * 256 + threadIdx.x;
    if (e >= N_EDGES) return;
    int r = ei[e], c = ei[N_EDGES + e];
    float4 a = ((const float4*)attr)[e];
    int slot = atomicAdd(&ptr[c], 1);
    float4* dst = entries + (size_t)slot * 2;
    dst[0] = a;
    int4 rr; rr.x = r; rr.y = 0; rr.z = 0; rr.w = 0;
    *(int4*)(dst + 1) = rr;
}

// ============ node init: x_ = x@iW + ib ============

__global__ __launch_bounds__(256) void k_init(const float* __restrict__ x,
    const float* __restrict__ iW, const float* __restrict__ ib,
    float* __restrict__ x_)
{
    int i = blockIdx.x * 256 + threadIdx.x;
    if (i >= N_NODES) return;
    const float4* xv = (const float4*)(x + (size_t)i * IN_DIM);
    float xi[IN_DIM];
    float4 a0 = xv[0], a1 = xv[1], a2 = xv[2], a3 = xv[3];
    xi[0]=a0.x; xi[1]=a0.y; xi[2]=a0.z; xi[3]=a0.w;
    xi[4]=a1.x; xi[5]=a1.y; xi[6]=a1.z; xi[7]=a1.w;
    xi[8]=a2.x; xi[9]=a2.y; xi[10]=a2.z; xi[11]=a2.w;
    xi[12]=a3.x; xi[13]=a3.y; xi[14]=a3.z; xi[15]=a3.w;
    float* dst = x_ + (size_t)i * S;
    #pragma unroll
    for (int j = 0; j < H; ++j) {
        float acc = ib[j];
        #pragma unroll
        for (int k = 0; k < IN_DIM; ++k) acc = fmaf(xi[k], iW[k*H + j], acc);
        dst[j] = acc;
    }
    dst[10] = 0.f; dst[11] = 0.f;
}

// ============ gather: deg -> dinv, and u0 = dinv * relu(x_) * gw0 ============
// 4 lanes per node; node's in-edges are contiguous [start, start+cnt)

__device__ __forceinline__ void ew_from_attr(const float4 a,
    const float* sW1, const float* sW2, float ew[H])
{
    float tt[H];
    #pragma unroll
    for (int j = 0; j < H; ++j)
        tt[j] = fmaxf(fmaf(a.x, sW1[j], fmaf(a.y, sW1[H+j],
                      fmaf(a.z, sW1[2*H+j], a.w*sW1[3*H+j]))), 0.f);
    #pragma unroll
    for (int ch = 0; ch < H; ++ch) {
        float v = 0.f;
        #pragma unroll
        for (int j = 0; j < H; ++j) v = fmaf(tt[j], sW2[j*H + ch], v);
        ew[ch] = fmaxf(v, 0.f);
    }
}

__global__ __launch_bounds__(256) void k_deg(const float4* __restrict__ entries,
    const int* __restrict__ start, const int* __restrict__ cnt,
    const float* __restrict__ W1, const float* __restrict__ W2,
    const float* __restrict__ x_, const float* __restrict__ gw0,
    float* __restrict__ dinv, float* __restrict__ u)
{
    __shared__ float sW1[4*H], sW2[H*H], sgw[H];
    int tid = threadIdx.x;
    for (int k = tid; k < 4*H; k += 256) sW1[k] = W1[k];
    for (int k = tid; k < H*H; k += 256) sW2[k] = W2[k];
    if (tid < H) sgw[tid] = gw0[tid];
    __syncthreads();
    int node = blockIdx.x * 64 + (tid >> 2);
    int r = tid & 3;
    if (node >= N_NODES) return;
    int st = start[node], n = cnt[node];
    float s[H];
    #pragma unroll
    for (int ch = 0; ch < H; ++ch) s[ch] = 0.f;
    for (int e = st + r; e < st + n; e += 4) {
        const float4* ent = entries + (size_t)e * 2;
        float4 a = ent[0];
        float ew[H];
        ew_from_attr(a, sW1, sW2, ew);
        #pragma unroll
        for (int ch = 0; ch < H; ++ch) s[ch] += ew[ch];
    }
    #pragma unroll
    for (int ch = 0; ch < H; ++ch) {
        s[ch] += __shfl_xor(s[ch], 1);
        s[ch] += __shfl_xor(s[ch], 2);
    }
    // all 4 lanes hold the full degree sum
    const float* xi = x_ + (size_t)node * S;
    float dv[H], uu[H];
    #pragma unroll
    for (int ch = 0; ch < H; ++ch) {
        float di = rsqrtf(1.0f + s[ch]);   // deg >= 1 (self loop)
        dv[ch] = di;
        uu[ch] = di * fmaxf(xi[ch], 0.f) * sgw[ch];
    }
    float* dd = dinv + (size_t)node * S;
    float* ud = u    + (size_t)node * S;
    if (r == 0) {
        *(float4*)(dd+0) = make_float4(dv[0],dv[1],dv[2],dv[3]);
        *(float4*)(ud+0) = make_float4(uu[0],uu[1],uu[2],uu[3]);
    } else if (r == 1) {
        *(float4*)(dd+4) = make_float4(dv[4],dv[5],dv[6],dv[7]);
        *(float4*)(ud+4) = make_float4(uu[4],uu[5],uu[6],uu[7]);
    } else if (r == 2) {
        *(float4*)(dd+8) = make_float4(dv[8],dv[9],0.f,0.f);
        *(float4*)(ud+8) = make_float4(uu[8],uu[9],0.f,0.f);
    }
}

// ============ fused layer: gather + agg + [x_,agg]@lin + x_ -> next u or out ============

template<int LAST>
__global__ __launch_bounds__(256) void k_layer(const float4* __restrict__ entries,
    const int* __restrict__ start, const int* __restrict__ cnt,
    const float* __restrict__ W1, const float* __restrict__ W2,
    const float* __restrict__ x_, const float* __restrict__ dinv,
    const float* __restrict__ uin,
    const float* __restrict__ lin, const float* __restrict__ gw_next,
    const float* __restrict__ gb, const float* __restrict__ oW,
    float* __restrict__ uout, float* __restrict__ out)
{
    __shared__ float sW1[4*H], sW2[H*H], slin[2*H*H], sgw[H], sgb[H], soW[4*H];
    int tid = threadIdx.x;
    for (int k = tid; k < 4*H; k += 256) sW1[k] = W1[k];
    for (int k = tid; k < H*H; k += 256) sW2[k] = W2[k];
    for (int k = tid; k < 2*H*H; k += 256) slin[k] = lin[k];
    if (tid < H) sgb[tid] = gb[tid];
    if (LAST) { if (tid < 4*H) soW[tid] = oW[tid]; }
    else      { if (tid >= 64 && tid < 64+H) sgw[tid-64] = gw_next[tid-64]; }
    __syncthreads();
    int node = blockIdx.x * 64 + (tid >> 2);
    int r = tid & 3;
    if (node >= N_NODES) return;
    int st = start[node], n = cnt[node];
    float s[H];
    #pragma unroll
    for (int ch = 0; ch < H; ++ch) s[ch] = 0.f;
    for (int e = st + r; e < st + n; e += 4) {
        const float4* ent = entries + (size_t)e * 2;
        float4 a = ent[0];
        int row = __float_as_int(ent[1].x);
        float ew[H];
        ew_from_attr(a, sW1, sW2, ew);
        const float4* up = (const float4*)(uin + (size_t)row * S);
        float4 u0 = up[0], u1 = up[1], u2 = up[2];
        float ur[H];
        ur[0]=u0.x; ur[1]=u0.y; ur[2]=u0.z; ur[3]=u0.w;
        ur[4]=u1.x; ur[5]=u1.y; ur[6]=u1.z; ur[7]=u1.w;
        ur[8]=u2.x; ur[9]=u2.y;
        #pragma unroll
        for (int ch = 0; ch < H; ++ch) s[ch] = fmaf(ew[ch], ur[ch], s[ch]);
    }
    #pragma unroll
    for (int ch = 0; ch < H; ++ch) {
        s[ch] += __shfl_xor(s[ch], 1);
        s[ch] += __shfl_xor(s[ch], 2);
    }
    // epilogue (all 4 lanes redundantly)
    const float* xi = x_   + (size_t)node * S;
    const float* di = dinv + (size_t)node * S;
    const float* ui = uin  + (size_t)node * S;
    float xv[H], agg[H];
    #pragma unroll
    for (int ch = 0; ch < H; ++ch) {
        xv[ch] = xi[ch];
        agg[ch] = di[ch] * (s[ch] + ui[ch]) + sgb[ch];  // + self-loop dinv^2*xp
    }
    float h[H];
    #pragma unroll
    for (int j = 0; j < H; ++j) {
        float acc = xv[j];                               // residual
        #pragma unroll
        for (int k = 0; k < H; ++k) acc = fmaf(xv[k], slin[k*H + j], acc);
        #pragma unroll
        for (int k = 0; k < H; ++k) acc = fmaf(agg[k], slin[(H+k)*H + j], acc);
        h[j] = acc;
    }
    if (!LAST) {
        float un[H];
        #pragma unroll
        for (int ch = 0; ch < H; ++ch)
            un[ch] = di[ch] * fmaxf(h[ch], 0.f) * sgw[ch];
        float* ud = uout + (size_t)node * S;
        if (r == 0)      *(float4*)(ud+0) = make_float4(un[0],un[1],un[2],un[3]);
        else if (r == 1) *(float4*)(ud+4) = make_float4(un[4],un[5],un[6],un[7]);
        else if (r == 2) *(float4*)(ud+8) = make_float4(un[8],un[9],0.f,0.f);
    } else {
        float z0 = 0.f, z1 = 0.f;
        #pragma unroll
        for (int k = 0; k < H; ++k) { z0 = fmaf(xv[k], soW[2*k],   z0);
                                      z1 = fmaf(xv[k], soW[2*k+1], z1); }
        #pragma unroll
        for (int k = 0; k < H; ++k) { float hr = fmaxf(h[k], 0.f);
                                      z0 = fmaf(hr, soW[2*(H+k)],   z0);
                                      z1 = fmaf(hr, soW[2*(H+k)+1], z1); }
        if (r == 0) out[node] = 1.0f / (1.0f + expf(z0 - z1));
    }
}

extern "C" void kernel_launch(void* const* d_in, const int* in_sizes, int n_in,
                              void* d_out, int out_size, void* d_ws, size_t ws_size,
                              hipStream_t stream)
{
    const float* x     = (const float*)d_in[0];
    const int*   ei    = (const int*)  d_in[1];
    const float* attr  = (const float*)d_in[2];
    const float* ew_W1 = (const float*)d_in[3];
    const float* ew_W2 = (const float*)d_in[4];
    const float* iW    = (const float*)d_in[5];
    const float* ib    = (const float*)d_in[6];
    const float* gcn_w = (const float*)d_in[7];
    const float* gcn_b = (const float*)d_in[8];
    const float* lin_W = (const float*)d_in[9];
    const float* oW    = (const float*)d_in[10];
    float* out = (float*)d_out;
    char* ws = (char*)d_ws;

    size_t o = 0;
    float4* entries = (float4*)(ws + o); o += (size_t)N_EDGES * 32;        // 102.4 MB
    float* x_   = (float*)(ws + o); o += (size_t)N_NODES * S * 4;          // 4.8 MB
    float* dinv = (float*)(ws + o); o += (size_t)N_NODES * S * 4;
    float* u_a  = (float*)(ws + o); o += (size_t)N_NODES * S * 4;
    float* u_b  = (float*)(ws + o); o += (size_t)N_NODES * S * 4;
    int* cnt    = (int*)(ws + o); o += (size_t)N_NODES * 4;
    int* start  = (int*)(ws + o); o += (size_t)N_NODES * 4;
    int* ptr    = (int*)(ws + o); o += (size_t)N_NODES * 4;
    int* bsum   = (int*)(ws + o); o += 512;

    dim3 blk(256);
    dim3 egrid((N_EDGES + 255) / 256);
    dim3 ngrid((N_NODES + 255) / 256);
    dim3 ggrid((N_NODES + 63) / 64);

    hipMemsetAsync(cnt, 0, (size_t)N_NODES * 4, stream);
    k_count<<<egrid, blk, 0, stream>>>(ei, cnt);
    k_scan1<<<NBLK_SCAN, 1024, 0, stream>>>(cnt, start, bsum);
    k_scan2<<<1, 128, 0, stream>>>(bsum);
    k_scan3<<<ngrid, blk, 0, stream>>>(start, bsum, ptr);
    k_init <<<ngrid, blk, 0, stream>>>(x, iW, ib, x_);
    k_fill <<<egrid, blk, 0, stream>>>(ei, attr, ptr, entries);
    k_deg  <<<ggrid, blk, 0, stream>>>(entries, start, cnt, ew_W1, ew_W2,
                                       x_, gcn_w, dinv, u_a);
    // layer 0: reads u_a, writes u_b
    k_layer<0><<<ggrid, blk, 0, stream>>>(entries, start, cnt, ew_W1, ew_W2,
        x_, dinv, u_a, lin_W + 0*2*H*H, gcn_w + 1*H, gcn_b + 0*H, oW, u_b, out);
    // layer 1: reads u_b, writes u_a
    k_layer<0><<<ggrid, blk, 0, stream>>>(entries, start, cnt, ew_W1, ew_W2,
        x_, dinv, u_b, lin_W + 1*2*H*H, gcn_w + 2*H, gcn_b + 1*H, oW, u_a, out);
    // layer 2: reads u_a, writes out
    k_layer<1><<<ggrid, blk, 0, stream>>>(entries, start, cnt, ew_W1, ew_W2,
        x_, dinv, u_a, lin_W + 2*2*H*H, nullptr, gcn_b + 2*H, oW, nullptr, out);
}

// Round 5
// 582.083 us; speedup vs baseline: 11.0933x; 1.0332x over previous
//
#include <hip/hip_runtime.h>
#include <math.h>

#define N_NODES 100000
#define N_EDGES 3200000
#define H 10
#define S 12          // padded per-node stride (floats): 48B, float4-aligned
#define IN_DIM 16
#define NBLK_SCAN 98  // ceil(100000/1024)

typedef int nint4 __attribute__((ext_vector_type(4)));   // native vec for nontemporal builtin

// ============ build phase: counting sort of edges by col ============

__global__ __launch_bounds__(256) void k_count(const int* __restrict__ ei,
                                               int* __restrict__ cnt)
{
    int e = blockIdx.x * 256 + threadIdx.x;
    if (e >= N_EDGES) return;
    atomicAdd(&cnt[ei[N_EDGES + e]], 1);
}

__global__ __launch_bounds__(1024) void k_scan1(const int* __restrict__ cnt,
    int* __restrict__ chunkscan, int* __restrict__ bsum)
{
    __shared__ int buf[2][1024];
    int tid = threadIdx.x;
    int gid = blockIdx.x * 1024 + tid;
    int v = (gid < N_NODES) ? cnt[gid] : 0;
    int cur = 0;
    buf[0][tid] = v;
    __syncthreads();
    int x = v;
    for (int off = 1; off < 1024; off <<= 1) {
        int t = (tid >= off) ? buf[cur][tid - off] : 0;
        x = buf[cur][tid] + t;
        buf[cur ^ 1][tid] = x;
        cur ^= 1;
        __syncthreads();
    }
    x = buf[cur][tid];
    if (gid < N_NODES) chunkscan[gid] = x - v;      // exclusive within chunk
    if (tid == 1023) bsum[blockIdx.x] = x;          // chunk total
}

__global__ __launch_bounds__(128) void k_scan2(int* __restrict__ bsum)
{
    __shared__ int buf[2][128];
    int tid = threadIdx.x;
    int v = (tid < NBLK_SCAN) ? bsum[tid] : 0;
    int cur = 0;
    buf[0][tid] = v;
    __syncthreads();
    int x = v;
    for (int off = 1; off < 128; off <<= 1) {
        int t = (tid >= off) ? buf[cur][tid - off] : 0;
        x = buf[cur][tid] + t;
        buf[cur ^ 1][tid] = x;
        cur ^= 1;
        __syncthreads();
    }
    x = buf[cur][tid];
    if (tid < NBLK_SCAN) bsum[tid] = x - v;         // exclusive over chunks
}

__global__ __launch_bounds__(256) void k_scan3(int* __restrict__ start,
    const int* __restrict__ bsum, int* __restrict__ ptr)
{
    int i = blockIdx.x * 256 + threadIdx.x;
    if (i >= N_NODES) return;
    int s = start[i] + bsum[i >> 10];
    start[i] = s;
    ptr[i] = s;
}

// ---- bf16 pack (round-to-nearest-even) ----
__device__ __forceinline__ unsigned pack2bf(float a, float b)
{
    unsigned ua = __float_as_uint(a), ub = __float_as_uint(b);
    unsigned ra = (ua + 0x7FFFu + ((ua >> 16) & 1u)) >> 16;
    unsigned rb = (ub + 0x7FFFu + ((ub >> 16) & 1u)) >> 16;
    return ra | (rb << 16);
}

// entry = 16B: {bf16(a0,a1), bf16(a2,a3), row, 0}
__global__ __launch_bounds__(256) void k_fill(const int* __restrict__ ei,
    const float* __restrict__ attr, int* __restrict__ ptr,
    nint4* __restrict__ entries)
{
    int e = blockIdx.x * 256 + threadIdx.x;
    if (e >= N_EDGES) return;
    int r = ei[e], c = ei[N_EDGES + e];
    float4 a = ((const float4*)attr)[e];
    int slot = atomicAdd(&ptr[c], 1);
    nint4 v;
    v.x = (int)pack2bf(a.x, a.y);
    v.y = (int)pack2bf(a.z, a.w);
    v.z = r;
    v.w = 0;
    __builtin_nontemporal_store(v, &entries[slot]);
}

// ============ shared helper: ew from packed attr ============

__device__ __forceinline__ void ew_from_packed(int px, int py,
    const float* sW1, const float* sW2, float ew[H])
{
    float ax = __uint_as_float(((unsigned)px) << 16);
    float ay = __uint_as_float(((unsigned)px) & 0xffff0000u);
    float az = __uint_as_float(((unsigned)py) << 16);
    float aw = __uint_as_float(((unsigned)py) & 0xffff0000u);
    float tt[H];
    #pragma unroll
    for (int j = 0; j < H; ++j)
        tt[j] = fmaxf(fmaf(ax, sW1[j], fmaf(ay, sW1[H+j],
                      fmaf(az, sW1[2*H+j], aw*sW1[3*H+j]))), 0.f);
    #pragma unroll
    for (int ch = 0; ch < H; ++ch) {
        float v = 0.f;
        #pragma unroll
        for (int j = 0; j < H; ++j) v = fmaf(tt[j], sW2[j*H + ch], v);
        ew[ch] = fmaxf(v, 0.f);
    }
}

// ============ deg pass (fused with node init):
//  x_ = x@iW + ib ; dinv = rsqrt(1+deg) ; u0 = dinv*relu(x_)*gw0 ============

__global__ __launch_bounds__(256) void k_deg(const nint4* __restrict__ entries,
    const int* __restrict__ start, const int* __restrict__ cnt,
    const float* __restrict__ W1, const float* __restrict__ W2,
    const float* __restrict__ x, const float* __restrict__ iW,
    const float* __restrict__ ib, const float* __restrict__ gw0,
    float* __restrict__ x_, float* __restrict__ dinv, float* __restrict__ u)
{
    __shared__ float sW1[4*H], sW2[H*H], siW[IN_DIM*H], sib[H], sgw[H];
    int tid = threadIdx.x;
    for (int k = tid; k < 4*H; k += 256) sW1[k] = W1[k];
    for (int k = tid; k < H*H; k += 256) sW2[k] = W2[k];
    for (int k = tid; k < IN_DIM*H; k += 256) siW[k] = iW[k];
    if (tid < H) sib[tid] = ib[tid];
    if (tid >= 32 && tid < 32+H) sgw[tid-32] = gw0[tid-32];
    __syncthreads();
    int node = blockIdx.x * 64 + (tid >> 2);
    int r = tid & 3;
    if (node >= N_NODES) return;
    int st = start[node], n = cnt[node];
    float s[H];
    #pragma unroll
    for (int ch = 0; ch < H; ++ch) s[ch] = 0.f;
    for (int e = st + r; e < st + n; e += 4) {
        nint4 ent = entries[e];
        float ew[H];
        ew_from_packed(ent.x, ent.y, sW1, sW2, ew);
        #pragma unroll
        for (int ch = 0; ch < H; ++ch) s[ch] += ew[ch];
    }
    #pragma unroll
    for (int ch = 0; ch < H; ++ch) {
        s[ch] += __shfl_xor(s[ch], 1);
        s[ch] += __shfl_xor(s[ch], 2);
    }
    // ---- fused node init: x_ = x@iW + ib (redundant across the 4 lanes) ----
    const float4* xv = (const float4*)(x + (size_t)node * IN_DIM);
    float xi[IN_DIM];
    float4 a0 = xv[0], a1 = xv[1], a2 = xv[2], a3 = xv[3];
    xi[0]=a0.x; xi[1]=a0.y; xi[2]=a0.z; xi[3]=a0.w;
    xi[4]=a1.x; xi[5]=a1.y; xi[6]=a1.z; xi[7]=a1.w;
    xi[8]=a2.x; xi[9]=a2.y; xi[10]=a2.z; xi[11]=a2.w;
    xi[12]=a3.x; xi[13]=a3.y; xi[14]=a3.z; xi[15]=a3.w;
    float xb[H], dv[H], uu[H];
    #pragma unroll
    for (int j = 0; j < H; ++j) {
        float acc = sib[j];
        #pragma unroll
        for (int k = 0; k < IN_DIM; ++k) acc = fmaf(xi[k], siW[k*H + j], acc);
        xb[j] = acc;
    }
    #pragma unroll
    for (int ch = 0; ch < H; ++ch) {
        float di = rsqrtf(1.0f + s[ch]);   // deg >= 1 (self loop)
        dv[ch] = di;
        uu[ch] = di * fmaxf(xb[ch], 0.f) * sgw[ch];
    }
    float* xd = x_   + (size_t)node * S;
    float* dd = dinv + (size_t)node * S;
    float* ud = u    + (size_t)node * S;
    if (r == 0) {
        *(float4*)(xd+0) = make_float4(xb[0],xb[1],xb[2],xb[3]);
        *(float4*)(dd+0) = make_float4(dv[0],dv[1],dv[2],dv[3]);
        *(float4*)(ud+0) = make_float4(uu[0],uu[1],uu[2],uu[3]);
    } else if (r == 1) {
        *(float4*)(xd+4) = make_float4(xb[4],xb[5],xb[6],xb[7]);
        *(float4*)(dd+4) = make_float4(dv[4],dv[5],dv[6],dv[7]);
        *(float4*)(ud+4) = make_float4(uu[4],uu[5],uu[6],uu[7]);
    } else if (r == 2) {
        *(float4*)(xd+8) = make_float4(xb[8],xb[9],0.f,0.f);
        *(float4*)(dd+8) = make_float4(dv[8],dv[9],0.f,0.f);
        *(float4*)(ud+8) = make_float4(uu[8],uu[9],0.f,0.f);
    }
}

// ============ fused layer: gather + agg + [x_,agg]@lin + x_ -> next u or out ============

template<int LAST>
__global__ __launch_bounds__(256) void k_layer(const nint4* __restrict__ entries,
    const int* __restrict__ start, const int* __restrict__ cnt,
    const float* __restrict__ W1, const float* __restrict__ W2,
    const float* __restrict__ x_, const float* __restrict__ dinv,
    const float* __restrict__ uin,
    const float* __restrict__ lin, const float* __restrict__ gw_next,
    const float* __restrict__ gb, const float* __restrict__ oW,
    float* __restrict__ uout, float* __restrict__ out)
{
    __shared__ float sW1[4*H], sW2[H*H], slin[2*H*H], sgw[H], sgb[H], soW[4*H];
    int tid = threadIdx.x;
    for (int k = tid; k < 4*H; k += 256) sW1[k] = W1[k];
    for (int k = tid; k < H*H; k += 256) sW2[k] = W2[k];
    for (int k = tid; k < 2*H*H; k += 256) slin[k] = lin[k];
    if (tid < H) sgb[tid] = gb[tid];
    if (LAST) { if (tid < 4*H) soW[tid] = oW[tid]; }
    else      { if (tid >= 64 && tid < 64+H) sgw[tid-64] = gw_next[tid-64]; }
    __syncthreads();
    int node = blockIdx.x * 64 + (tid >> 2);
    int r = tid & 3;
    if (node >= N_NODES) return;
    int st = start[node], n = cnt[node];
    float s[H];
    #pragma unroll
    for (int ch = 0; ch < H; ++ch) s[ch] = 0.f;
    for (int e = st + r; e < st + n; e += 4) {
        nint4 ent = entries[e];
        float ew[H];
        ew_from_packed(ent.x, ent.y, sW1, sW2, ew);
        const float4* up = (const float4*)(uin + (size_t)ent.z * S);
        float4 u0 = up[0], u1 = up[1], u2 = up[2];
        float ur[H];
        ur[0]=u0.x; ur[1]=u0.y; ur[2]=u0.z; ur[3]=u0.w;
        ur[4]=u1.x; ur[5]=u1.y; ur[6]=u1.z; ur[7]=u1.w;
        ur[8]=u2.x; ur[9]=u2.y;
        #pragma unroll
        for (int ch = 0; ch < H; ++ch) s[ch] = fmaf(ew[ch], ur[ch], s[ch]);
    }
    #pragma unroll
    for (int ch = 0; ch < H; ++ch) {
        s[ch] += __shfl_xor(s[ch], 1);
        s[ch] += __shfl_xor(s[ch], 2);
    }
    // epilogue (all 4 lanes redundantly)
    const float* xi = x_   + (size_t)node * S;
    const float* di = dinv + (size_t)node * S;
    const float* ui = uin  + (size_t)node * S;
    float xv[H], agg[H];
    #pragma unroll
    for (int ch = 0; ch < H; ++ch) {
        xv[ch] = xi[ch];
        agg[ch] = di[ch] * (s[ch] + ui[ch]) + sgb[ch];  // + self-loop dinv^2*xp
    }
    float h[H];
    #pragma unroll
    for (int j = 0; j < H; ++j) {
        float acc = xv[j];                               // residual
        #pragma unroll
        for (int k = 0; k < H; ++k) acc = fmaf(xv[k], slin[k*H + j], acc);
        #pragma unroll
        for (int k = 0; k < H; ++k) acc = fmaf(agg[k], slin[(H+k)*H + j], acc);
        h[j] = acc;
    }
    if (!LAST) {
        float un[H];
        #pragma unroll
        for (int ch = 0; ch < H; ++ch)
            un[ch] = di[ch] * fmaxf(h[ch], 0.f) * sgw[ch];
        float* ud = uout + (size_t)node * S;
        if (r == 0)      *(float4*)(ud+0) = make_float4(un[0],un[1],un[2],un[3]);
        else if (r == 1) *(float4*)(ud+4) = make_float4(un[4],un[5],un[6],un[7]);
        else if (r == 2) *(float4*)(ud+8) = make_float4(un[8],un[9],0.f,0.f);
    } else {
        float z0 = 0.f, z1 = 0.f;
        #pragma unroll
        for (int k = 0; k < H; ++k) { z0 = fmaf(xv[k], soW[2*k],   z0);
                                      z1 = fmaf(xv[k], soW[2*k+1], z1); }
        #pragma unroll
        for (int k = 0; k < H; ++k) { float hr = fmaxf(h[k], 0.f);
                                      z0 = fmaf(hr, soW[2*(H+k)],   z0);
                                      z1 = fmaf(hr, soW[2*(H+k)+1], z1); }
        if (r == 0) out[node] = 1.0f / (1.0f + expf(z0 - z1));
    }
}

extern "C" void kernel_launch(void* const* d_in, const int* in_sizes, int n_in,
                              void* d_out, int out_size, void* d_ws, size_t ws_size,
                              hipStream_t stream)
{
    const float* x     = (const float*)d_in[0];
    const int*   ei    = (const int*)  d_in[1];
    const float* attr  = (const float*)d_in[2];
    const float* ew_W1 = (const float*)d_in[3];
    const float* ew_W2 = (const float*)d_in[4];
    const float* iW    = (const float*)d_in[5];
    const float* ib    = (const float*)d_in[6];
    const float* gcn_w = (const float*)d_in[7];
    const float* gcn_b = (const float*)d_in[8];
    const float* lin_W = (const float*)d_in[9];
    const float* oW    = (const float*)d_in[10];
    float* out = (float*)d_out;
    char* ws = (char*)d_ws;

    size_t o = 0;
    nint4* entries = (nint4*)(ws + o); o += (size_t)N_EDGES * 16;          // 51.2 MB
    float* x_   = (float*)(ws + o); o += (size_t)N_NODES * S * 4;          // 4.8 MB
    float* dinv = (float*)(ws + o); o += (size_t)N_NODES * S * 4;
    float* u_a  = (float*)(ws + o); o += (size_t)N_NODES * S * 4;
    float* u_b  = (float*)(ws + o); o += (size_t)N_NODES * S * 4;
    int* cnt    = (int*)(ws + o); o += (size_t)N_NODES * 4;
    int* start  = (int*)(ws + o); o += (size_t)N_NODES * 4;
    int* ptr    = (int*)(ws + o); o += (size_t)N_NODES * 4;
    int* bsum   = (int*)(ws + o); o += 512;

    dim3 blk(256);
    dim3 egrid((N_EDGES + 255) / 256);
    dim3 ngrid((N_NODES + 255) / 256);
    dim3 ggrid((N_NODES + 63) / 64);

    (void)hipMemsetAsync(cnt, 0, (size_t)N_NODES * 4, stream);
    k_count<<<egrid, blk, 0, stream>>>(ei, cnt);
    k_scan1<<<NBLK_SCAN, 1024, 0, stream>>>(cnt, start, bsum);
    k_scan2<<<1, 128, 0, stream>>>(bsum);
    k_scan3<<<ngrid, blk, 0, stream>>>(start, bsum, ptr);
    k_fill <<<egrid, blk, 0, stream>>>(ei, attr, ptr, entries);
    k_deg  <<<ggrid, blk, 0, stream>>>(entries, start, cnt, ew_W1, ew_W2,
                                       x, iW, ib, gcn_w, x_, dinv, u_a);
    // layer 0: reads u_a, writes u_b
    k_layer<0><<<ggrid, blk, 0, stream>>>(entries, start, cnt, ew_W1, ew_W2,
        x_, dinv, u_a, lin_W + 0*2*H*H, gcn_w + 1*H, gcn_b + 0*H, oW, u_b, out);
    // layer 1: reads u_b, writes u_a
    k_layer<0><<<ggrid, blk, 0, stream>>>(entries, start, cnt, ew_W1, ew_W2,
        x_, dinv, u_b, lin_W + 1*2*H*H, gcn_w + 2*H, gcn_b + 1*H, oW, u_a, out);
    // layer 2: reads u_a, writes out
    k_layer<1><<<ggrid, blk, 0, stream>>>(entries, start, cnt, ew_W1, ew_W2,
        x_, dinv, u_a, lin_W + 2*2*H*H, nullptr, gcn_b + 2*H, oW, nullptr, out);
}